// Round 8
// baseline (155.403 us; speedup 1.0000x reference)
//
#include <hip/hip_runtime.h>

#define S_LEN 2304   // 48*48
#define CDIM  512
#define NHEAD 8

typedef __attribute__((ext_vector_type(4))) float f32x4;
typedef __attribute__((ext_vector_type(8))) _Float16 f16x8;
typedef __attribute__((ext_vector_type(2))) __fp16 fp16x2r;  // cvt_pkrtz native type
typedef _Float16 h16;

// softmax runs in exp2 domain: q pre-scaled by 1/sqrt(64) * log2(e)
#define QSCALE 0.18033688011112042f

__device__ __forceinline__ float fexp2(float x) {
#if __has_builtin(__builtin_amdgcn_exp2f)
    return __builtin_amdgcn_exp2f(x);
#else
    return exp2f(x);
#endif
}

// async global->LDS, 16B per lane; LDS dest = wave-uniform base + lane*16
__device__ __forceinline__ void gll16(const h16* g, h16* l) {
    __builtin_amdgcn_global_load_lds(
        (const __attribute__((address_space(1))) unsigned int*)g,
        (__attribute__((address_space(3))) unsigned int*)l, 16, 0, 0);
}

// ---------------------------------------------------------------------------
// Kernel 0a: transpose+convert x[b][c][s] fp32 -> xT[b][s][c] fp16
// ---------------------------------------------------------------------------
__global__ __launch_bounds__(256) void xpose_x(
    const float* __restrict__ x, h16* __restrict__ xT)
{
    const int s0 = blockIdx.x * 64;
    const int c0 = blockIdx.y * 64;
    const int b  = blockIdx.z;
    __shared__ h16 Ts[64][76];

    const int t  = threadIdx.x;
    const int cq = t >> 4;
    const int sq = t & 15;

    const float* xb = x + ((size_t)b * CDIM + c0 + cq * 4) * S_LEN + s0 + sq * 4;
    float4 r0 = *(const float4*)(xb);
    float4 r1 = *(const float4*)(xb + S_LEN);
    float4 r2 = *(const float4*)(xb + 2 * S_LEN);
    float4 r3 = *(const float4*)(xb + 3 * S_LEN);

    union { h16 h[4]; uint2 u; } pk;
    pk.h[0]=(h16)r0.x; pk.h[1]=(h16)r1.x; pk.h[2]=(h16)r2.x; pk.h[3]=(h16)r3.x;
    *(uint2*)&Ts[sq*4+0][cq*4] = pk.u;
    pk.h[0]=(h16)r0.y; pk.h[1]=(h16)r1.y; pk.h[2]=(h16)r2.y; pk.h[3]=(h16)r3.y;
    *(uint2*)&Ts[sq*4+1][cq*4] = pk.u;
    pk.h[0]=(h16)r0.z; pk.h[1]=(h16)r1.z; pk.h[2]=(h16)r2.z; pk.h[3]=(h16)r3.z;
    *(uint2*)&Ts[sq*4+2][cq*4] = pk.u;
    pk.h[0]=(h16)r0.w; pk.h[1]=(h16)r1.w; pk.h[2]=(h16)r2.w; pk.h[3]=(h16)r3.w;
    *(uint2*)&Ts[sq*4+3][cq*4] = pk.u;

    __syncthreads();
    const int s  = t >> 2;
    const int cc = (t & 3) * 16;
    uint2 a0 = *(uint2*)&Ts[s][cc + 0];
    uint2 a1 = *(uint2*)&Ts[s][cc + 4];
    uint2 a2 = *(uint2*)&Ts[s][cc + 8];
    uint2 a3 = *(uint2*)&Ts[s][cc + 12];
    h16* dst = xT + ((size_t)b * S_LEN + s0 + s) * CDIM + c0 + cc;
    uint4 w0 = make_uint4(a0.x, a0.y, a1.x, a1.y);
    uint4 w1 = make_uint4(a2.x, a2.y, a3.x, a3.y);
    *(uint4*)dst       = w0;
    *(uint4*)(dst + 8) = w1;
}

// ---------------------------------------------------------------------------
// Kernel 0b: convert Wqkv (1536x512) and Wout (512x512) fp32 -> fp16
// ---------------------------------------------------------------------------
__global__ __launch_bounds__(256) void wconv(
    const float* __restrict__ Wq, const float* __restrict__ Wo,
    h16* __restrict__ Wq_h, h16* __restrict__ Wo_h)
{
    const int NQ = 1536 * 512;
    const int NO = 512 * 512;
    int i = (blockIdx.x * 256 + threadIdx.x) * 4;
    if (i >= NQ + NO) return;
    float4 v;
    h16* dst;
    if (i < NQ) { v = *(const float4*)(Wq + i);        dst = Wq_h + i; }
    else        { v = *(const float4*)(Wo + (i - NQ)); dst = Wo_h + (i - NQ); }
    union { h16 h[4]; uint2 u; } pk;
    pk.h[0]=(h16)v.x; pk.h[1]=(h16)v.y; pk.h[2]=(h16)v.z; pk.h[3]=(h16)v.w;
    *(uint2*)dst = pk.u;
}

// ---------------------------------------------------------------------------
// Kernel 1: QKV projection, fp16 MFMA. q rows get *QSCALE (softmax exp2 domain).
// ---------------------------------------------------------------------------
__global__ __launch_bounds__(256) void gemm_qkv(
    const h16* __restrict__ Wh, const float* __restrict__ bqkv,
    const h16* __restrict__ xT, h16* __restrict__ qT, h16* __restrict__ kT,
    h16* __restrict__ vN)
{
    const int n0 = blockIdx.x * 128;
    const int m0 = blockIdx.y * 128;
    const int b  = blockIdx.z;
    __shared__ h16 Ws[128 * 64];
    __shared__ h16 Xs[128 * 64];

    const int tid = threadIdx.x;
    const int lid = tid & 63, w = tid >> 6;
    const int g = lid >> 4, ln = lid & 15;
    const int wm = w & 1, wn = w >> 1;
    const int srow = lid >> 3;
    const int sblk = (lid & 7) ^ (srow & 7);

    f32x4 acc[4][4];
#pragma unroll
    for (int i = 0; i < 4; i++)
#pragma unroll
        for (int j = 0; j < 4; j++) acc[i][j] = (f32x4)0.f;

    const h16* Wbase = Wh + (size_t)m0 * CDIM;
    const h16* Xbase = xT + ((size_t)b * S_LEN + n0) * CDIM;
    const bool vblk = (m0 >= 1024);

    for (int kt = 0; kt < CDIM; kt += 64) {
        __syncthreads();
#pragma unroll
        for (int i = 0; i < 4; i++) {
            const int row0 = w * 32 + i * 8;
            gll16(Wbase + (size_t)(row0 + srow) * CDIM + kt + sblk * 8, &Ws[row0 * 64]);
            gll16(Xbase + (size_t)(row0 + srow) * CDIM + kt + sblk * 8, &Xs[row0 * 64]);
        }
        __syncthreads();

#pragma unroll
        for (int kc = 0; kc < 2; kc++) {
            f16x8 af[4], bf[4];
#pragma unroll
            for (int i = 0; i < 4; i++) {
                const int ra = wm * 64 + i * 16 + ln;
                const int ca = (kc * 64 + g * 16) ^ ((ra & 7) << 4);
                af[i] = *(const f16x8*)&Ws[ra * 64 + ca / 2];
                const int rb = wn * 64 + i * 16 + ln;
                const int cb = (kc * 64 + g * 16) ^ ((rb & 7) << 4);
                bf[i] = *(const f16x8*)&Xs[rb * 64 + cb / 2];
            }
            if (!vblk) {
#pragma unroll
                for (int i = 0; i < 4; i++)
#pragma unroll
                    for (int j = 0; j < 4; j++)
                        acc[i][j] = __builtin_amdgcn_mfma_f32_16x16x32_f16(
                            af[i], bf[j], acc[i][j], 0, 0, 0);
            } else {
#pragma unroll
                for (int i = 0; i < 4; i++)
#pragma unroll
                    for (int j = 0; j < 4; j++)
                        acc[i][j] = __builtin_amdgcn_mfma_f32_16x16x32_f16(
                            bf[i], af[j], acc[i][j], 0, 0, 0);
            }
        }
    }

    if (!vblk) {
#pragma unroll
        for (int i = 0; i < 4; i++) {
            const int mb = m0 + wm * 64 + i * 16 + 4 * g;
            const float4 bv = *(const float4*)&bqkv[mb];
            const int mloc = mb & 511;
            const int hh = mloc >> 6, d0 = mloc & 63;
            const bool isq = (mb < 512);
            const float scl = isq ? QSCALE : 1.0f;
            h16* base = (isq ? qT : kT);
#pragma unroll
            for (int j = 0; j < 4; j++) {
                const int n = n0 + wn * 64 + j * 16 + ln;
                union { h16 h[4]; uint2 u; } pk;
                pk.h[0] = (h16)((acc[i][j][0] + bv.x) * scl);
                pk.h[1] = (h16)((acc[i][j][1] + bv.y) * scl);
                pk.h[2] = (h16)((acc[i][j][2] + bv.z) * scl);
                pk.h[3] = (h16)((acc[i][j][3] + bv.w) * scl);
                *(uint2*)(base + (((size_t)b * 8 + hh) * S_LEN + n) * 64 + d0) = pk.u;
            }
        }
    } else {
#pragma unroll
        for (int j = 0; j < 4; j++) {
            const int m = m0 + wm * 64 + j * 16 + ln;
            const float bias = bqkv[m];
            const int mloc = m - 1024;
            const int hh = mloc >> 6, d = mloc & 63;
            h16* base = vN + (((size_t)b * 8 + hh) * 64 + d) * S_LEN;
#pragma unroll
            for (int i = 0; i < 4; i++) {
                const int nb = n0 + wn * 64 + i * 16 + 4 * g;
                union { h16 h[4]; uint2 u; } pk;
                pk.h[0] = (h16)(acc[i][j][0] + bias);
                pk.h[1] = (h16)(acc[i][j][1] + bias);
                pk.h[2] = (h16)(acc[i][j][2] + bias);
                pk.h[3] = (h16)(acc[i][j][3] + bias);
                *(uint2*)(base + nb) = pk.u;
            }
        }
    }
}

// ---------------------------------------------------------------------------
// Kernel 2: flash attention fp16, exp2-domain softmax.
//  - 96-query blocks: 6 waves x 16 rows, 384 threads.
//    grid = 24*8*4 = 768 = EXACTLY 3 blocks/CU (no dispatch tail);
//    LDS 44KB -> 3 blocks/CU resident = 18 waves/CU.
//  - Q in registers; K/V double-buffered via global_load_lds (16 x 8-row chunks
//    split over 6 waves); defer-max; ones-MFMA l-sum.
// ---------------------------------------------------------------------------
__global__ __launch_bounds__(384, 4) void attn_f16(
    const h16* __restrict__ qT, const h16* __restrict__ kT,
    const h16* __restrict__ vN, h16* __restrict__ attT)
{
    const int s0 = blockIdx.x * 96;
    const int h  = blockIdx.y;
    const int b  = blockIdx.z;
    __shared__ h16 Ks[2][64 * 64];
    __shared__ h16 Vs[2][64 * 64];
    __shared__ h16 Ps[96 * 64];

    const int tid = threadIdx.x;
    const int lid = tid & 63, w = tid >> 6;      // w = 0..5
    const int g = lid >> 4, ln = lid & 15;
    const int srow = lid >> 3;
    const int sblk = (lid & 7) ^ (srow & 7);

    const h16* qb = qT + ((size_t)b * 8 + h) * S_LEN * 64;
    const h16* kb = kT + ((size_t)b * 8 + h) * S_LEN * 64;
    const h16* vb = vN + ((size_t)b * 8 + h) * 64 * S_LEN;

    // Q straight to registers (global layout is linear; swizzle is LDS-only)
    f16x8 qreg[2];
    {
        const h16* qrow = qb + (size_t)(s0 + 16 * w + ln) * 64;
        qreg[0] = *(const f16x8*)(qrow + g * 8);
        qreg[1] = *(const f16x8*)(qrow + 32 + g * 8);
    }

    // prologue: stage tile 0 of K/V (16 chunks of 8 rows, split over 6 waves)
    for (int c = w; c < 16; c += 6) {
        if (c < 8)
            gll16(kb + (size_t)(c * 8 + srow) * 64 + sblk * 8, &Ks[0][c * 8 * 64]);
        else
            gll16(vb + (size_t)((c - 8) * 8 + srow) * S_LEN + sblk * 8,
                  &Vs[0][(c - 8) * 8 * 64]);
    }
    __syncthreads();

    f16x8 ones;
#pragma unroll
    for (int i = 0; i < 8; i++) ones[i] = (h16)1.0f;

    float m_run = -1e30f;
    f32x4 oacc[4], lacc;
#pragma unroll
    for (int i = 0; i < 4; i++) oacc[i] = (f32x4)0.f;
    lacc = (f32x4)0.f;

    int cur = 0;
    for (int kt = 0; kt < S_LEN; kt += 64, cur ^= 1) {
        // prefetch next K/V tile into the other buffer (drained by end barrier)
        if (kt + 64 < S_LEN) {
            for (int c = w; c < 16; c += 6) {
                if (c < 8)
                    gll16(kb + (size_t)(kt + 64 + c * 8 + srow) * 64 + sblk * 8,
                          &Ks[cur ^ 1][c * 8 * 64]);
                else
                    gll16(vb + (size_t)((c - 8) * 8 + srow) * S_LEN + kt + 64 + sblk * 8,
                          &Vs[cur ^ 1][(c - 8) * 8 * 64]);
            }
        }
        const h16* Kc = Ks[cur];
        const h16* Vc = Vs[cur];

        // S^T = mfma(Kf, Qf): lane holds S^T[t=16tb+4g+r][s=16w+ln] (exp2 domain)
        f32x4 sacc[4];
#pragma unroll
        for (int tb = 0; tb < 4; tb++) sacc[tb] = (f32x4)0.f;
#pragma unroll
        for (int c = 0; c < 2; c++) {
#pragma unroll
            for (int tb = 0; tb < 4; tb++) {
                const int row = tb * 16 + ln;
                const int cb = (c * 64 + g * 16) ^ ((row & 7) << 4);
                f16x8 kf = *(const f16x8*)&Kc[row * 64 + cb / 2];
                sacc[tb] = __builtin_amdgcn_mfma_f32_16x16x32_f16(kf, qreg[c], sacc[tb], 0, 0, 0);
            }
        }

        // column max (pairwise tree) + cross-group reduce
        float m0 = fmaxf(fmaxf(sacc[0][0], sacc[0][1]), fmaxf(sacc[0][2], sacc[0][3]));
        float m1 = fmaxf(fmaxf(sacc[1][0], sacc[1][1]), fmaxf(sacc[1][2], sacc[1][3]));
        float m2 = fmaxf(fmaxf(sacc[2][0], sacc[2][1]), fmaxf(sacc[2][2], sacc[2][3]));
        float m3 = fmaxf(fmaxf(sacc[3][0], sacc[3][1]), fmaxf(sacc[3][2], sacc[3][3]));
        float mloc = fmaxf(fmaxf(m0, m1), fmaxf(m2, m3));
        mloc = fmaxf(mloc, __shfl_xor(mloc, 16));
        mloc = fmaxf(mloc, __shfl_xor(mloc, 32));

        // defer-max: rescale only when tile max grew past threshold
        if (!__all(mloc <= m_run + 8.0f)) {
            const float mnew = fmaxf(m_run, mloc);
            const float resc = fexp2(m_run - mnew);
#pragma unroll
            for (int db = 0; db < 4; db++)
#pragma unroll
                for (int r = 0; r < 4; r++) oacc[db][r] *= resc;
#pragma unroll
            for (int r = 0; r < 4; r++) lacc[r] *= resc;
            m_run = mnew;
        }

        // P = exp2(S - m_run), pack rtz, write wave-private LDS rows
#pragma unroll
        for (int tb = 0; tb < 4; tb++) {
            union { fp16x2r v[2]; uint2 u; } pk;
            pk.v[0] = __builtin_amdgcn_cvt_pkrtz(fexp2(sacc[tb][0] - m_run),
                                                 fexp2(sacc[tb][1] - m_run));
            pk.v[1] = __builtin_amdgcn_cvt_pkrtz(fexp2(sacc[tb][2] - m_run),
                                                 fexp2(sacc[tb][3] - m_run));
            const int cb = (tb * 32 + g * 8) ^ ((ln & 7) << 4);
            *(uint2*)&Ps[(16 * w + ln) * 64 + cb / 2] = pk.u;
        }

        // O += mfma(Vf, Pf); l += mfma(ones, Pf)
#pragma unroll
        for (int c = 0; c < 2; c++) {
            const int cp = (c * 64 + g * 16) ^ ((ln & 7) << 4);
            f16x8 pf = *(const f16x8*)&Ps[(16 * w + ln) * 64 + cp / 2];
            lacc = __builtin_amdgcn_mfma_f32_16x16x32_f16(ones, pf, lacc, 0, 0, 0);
#pragma unroll
            for (int db = 0; db < 4; db++) {
                const int row = db * 16 + ln;
                const int cb = (c * 64 + g * 16) ^ ((row & 7) << 4);
                f16x8 vf = *(const f16x8*)&Vc[row * 64 + cb / 2];
                oacc[db] = __builtin_amdgcn_mfma_f32_16x16x32_f16(vf, pf, oacc[db], 0, 0, 0);
            }
        }
        __syncthreads();   // next tile staged (vmcnt drain) + Ks/Vs reads done
    }

    // epilogue: attT[b][s0+16w+ln][h*64 + d], 8B chunks
    const float inv = 1.0f / lacc[0];
    h16* ob = attT + ((size_t)b * S_LEN + s0 + 16 * w + ln) * CDIM + h * 64;
#pragma unroll
    for (int db = 0; db < 4; db++) {
        union { h16 h[4]; uint2 u; } pk;
#pragma unroll
        for (int r = 0; r < 4; r++) pk.h[r] = (h16)(oacc[db][r] * inv);
        *(uint2*)(ob + db * 16 + 4 * g) = pk.u;
    }
}

// ---------------------------------------------------------------------------
// Kernel 3: output projection. A=attT[b][n][k], B=Wout_h[m][k].
// ---------------------------------------------------------------------------
__global__ __launch_bounds__(256) void gemm_out(
    const h16* __restrict__ attT, const h16* __restrict__ Wh,
    const float* __restrict__ bout, float* __restrict__ out)
{
    const int n0 = blockIdx.x * 128;
    const int m0 = blockIdx.y * 128;
    const int b  = blockIdx.z;
    __shared__ h16 Ws[128 * 64];
    __shared__ h16 Xs[128 * 64];

    const int tid = threadIdx.x;
    const int lid = tid & 63, w = tid >> 6;
    const int g = lid >> 4, ln = lid & 15;
    const int wm = w & 1, wn = w >> 1;
    const int srow = lid >> 3;
    const int sblk = (lid & 7) ^ (srow & 7);

    f32x4 acc[4][4];
#pragma unroll
    for (int i = 0; i < 4; i++)
#pragma unroll
        for (int j = 0; j < 4; j++) acc[i][j] = (f32x4)0.f;

    const h16* Wbase = Wh + (size_t)m0 * CDIM;
    const h16* Xbase = attT + ((size_t)b * S_LEN + n0) * CDIM;

    for (int kt = 0; kt < CDIM; kt += 64) {
        __syncthreads();
#pragma unroll
        for (int i = 0; i < 4; i++) {
            const int row0 = w * 32 + i * 8;
            gll16(Wbase + (size_t)(row0 + srow) * CDIM + kt + sblk * 8, &Ws[row0 * 64]);
            gll16(Xbase + (size_t)(row0 + srow) * CDIM + kt + sblk * 8, &Xs[row0 * 64]);
        }
        __syncthreads();

#pragma unroll
        for (int kc = 0; kc < 2; kc++) {
            f16x8 af[4], bf[4];
#pragma unroll
            for (int i = 0; i < 4; i++) {
                const int ra = wm * 64 + i * 16 + ln;
                const int ca = (kc * 64 + g * 16) ^ ((ra & 7) << 4);
                af[i] = *(const f16x8*)&Ws[ra * 64 + ca / 2];
                const int rb = wn * 64 + i * 16 + ln;
                const int cb = (kc * 64 + g * 16) ^ ((rb & 7) << 4);
                bf[i] = *(const f16x8*)&Xs[rb * 64 + cb / 2];
            }
#pragma unroll
            for (int i = 0; i < 4; i++)
#pragma unroll
                for (int j = 0; j < 4; j++)
                    acc[i][j] = __builtin_amdgcn_mfma_f32_16x16x32_f16(
                        bf[i], af[j], acc[i][j], 0, 0, 0);
        }
    }

#pragma unroll
    for (int j = 0; j < 4; j++) {
        const int m = m0 + wm * 64 + j * 16 + ln;
        const float bias = bout[m];
        float* base = out + ((size_t)b * CDIM + m) * S_LEN;
#pragma unroll
        for (int i = 0; i < 4; i++) {
            const int nb = n0 + wn * 64 + i * 16 + 4 * g;
            float4 o;
            o.x = acc[i][j][0] + bias;
            o.y = acc[i][j][1] + bias;
            o.z = acc[i][j][2] + bias;
            o.w = acc[i][j][3] + bias;
            *(float4*)(base + nb) = o;
        }
    }
}

// ---------------------------------------------------------------------------
extern "C" void kernel_launch(void* const* d_in, const int* in_sizes, int n_in,
                              void* d_out, int out_size, void* d_ws, size_t ws_size,
                              hipStream_t stream)
{
    const float* x    = (const float*)d_in[0];
    const float* Wqkv = (const float*)d_in[1];
    const float* bqkv = (const float*)d_in[2];
    const float* Wout = (const float*)d_in[3];
    const float* bout = (const float*)d_in[4];
    float* out = (float*)d_out;

    h16* xT   = (h16*)d_ws;                          // [4][2304][512]
    h16* Wq_h = xT   + (size_t)4 * S_LEN * CDIM;     // [1536][512]
    h16* Wo_h = Wq_h + (size_t)1536 * 512;           // [512][512]
    h16* qT   = Wo_h + (size_t)512 * 512;            // [4][8][2304][64]
    h16* kT   = qT   + (size_t)4 * 8 * S_LEN * 64;
    h16* vN   = kT   + (size_t)4 * 8 * S_LEN * 64;   // [4][8][64][2304]
    h16* attT = vN   + (size_t)4 * 8 * S_LEN * 64;   // [4][2304][512]

    xpose_x <<<dim3(36, 8, 4),  256, 0, stream>>>(x, xT);
    wconv   <<<1024,            256, 0, stream>>>(Wqkv, Wout, Wq_h, Wo_h);
    gemm_qkv<<<dim3(18, 12, 4), 256, 0, stream>>>(Wq_h, bqkv, xT, qT, kT, vN);
    attn_f16<<<dim3(24, 8, 4),  384, 0, stream>>>(qT, kT, vN, attT);
    gemm_out<<<dim3(18, 4, 4),  256, 0, stream>>>(attT, Wo_h, bout, out);
}

// Round 9
// 136.486 us; speedup vs baseline: 1.1386x; 1.1386x over previous
//
#include <hip/hip_runtime.h>

#define S_LEN 2304   // 48*48
#define CDIM  512
#define NHEAD 8

typedef __attribute__((ext_vector_type(4)))  float f32x4;
typedef __attribute__((ext_vector_type(16))) float f32x16;
typedef __attribute__((ext_vector_type(8)))  _Float16 f16x8;
typedef __attribute__((ext_vector_type(2)))  __fp16 fp16x2r;  // cvt_pkrtz native type
typedef _Float16 h16;

// softmax runs in exp2 domain: q pre-scaled by 1/sqrt(64) * log2(e)
#define QSCALE 0.18033688011112042f

__device__ __forceinline__ float fexp2(float x) {
#if __has_builtin(__builtin_amdgcn_exp2f)
    return __builtin_amdgcn_exp2f(x);
#else
    return exp2f(x);
#endif
}

__device__ __forceinline__ unsigned cvtpk(float a, float b) {
    union { fp16x2r v; unsigned u; } c;
    c.v = __builtin_amdgcn_cvt_pkrtz(a, b);
    return c.u;
}

// async global->LDS, 16B per lane; LDS dest = wave-uniform base + lane*16
__device__ __forceinline__ void gll16(const h16* g, h16* l) {
    __builtin_amdgcn_global_load_lds(
        (const __attribute__((address_space(1))) unsigned int*)g,
        (__attribute__((address_space(3))) unsigned int*)l, 16, 0, 0);
}

// ---------------------------------------------------------------------------
// Kernel 0a: transpose+convert x[b][c][s] fp32 -> xT[b][s][c] fp16
// ---------------------------------------------------------------------------
__global__ __launch_bounds__(256) void xpose_x(
    const float* __restrict__ x, h16* __restrict__ xT)
{
    const int s0 = blockIdx.x * 64;
    const int c0 = blockIdx.y * 64;
    const int b  = blockIdx.z;
    __shared__ h16 Ts[64][76];

    const int t  = threadIdx.x;
    const int cq = t >> 4;
    const int sq = t & 15;

    const float* xb = x + ((size_t)b * CDIM + c0 + cq * 4) * S_LEN + s0 + sq * 4;
    float4 r0 = *(const float4*)(xb);
    float4 r1 = *(const float4*)(xb + S_LEN);
    float4 r2 = *(const float4*)(xb + 2 * S_LEN);
    float4 r3 = *(const float4*)(xb + 3 * S_LEN);

    union { h16 h[4]; uint2 u; } pk;
    pk.h[0]=(h16)r0.x; pk.h[1]=(h16)r1.x; pk.h[2]=(h16)r2.x; pk.h[3]=(h16)r3.x;
    *(uint2*)&Ts[sq*4+0][cq*4] = pk.u;
    pk.h[0]=(h16)r0.y; pk.h[1]=(h16)r1.y; pk.h[2]=(h16)r2.y; pk.h[3]=(h16)r3.y;
    *(uint2*)&Ts[sq*4+1][cq*4] = pk.u;
    pk.h[0]=(h16)r0.z; pk.h[1]=(h16)r1.z; pk.h[2]=(h16)r2.z; pk.h[3]=(h16)r3.z;
    *(uint2*)&Ts[sq*4+2][cq*4] = pk.u;
    pk.h[0]=(h16)r0.w; pk.h[1]=(h16)r1.w; pk.h[2]=(h16)r2.w; pk.h[3]=(h16)r3.w;
    *(uint2*)&Ts[sq*4+3][cq*4] = pk.u;

    __syncthreads();
    const int s  = t >> 2;
    const int cc = (t & 3) * 16;
    uint2 a0 = *(uint2*)&Ts[s][cc + 0];
    uint2 a1 = *(uint2*)&Ts[s][cc + 4];
    uint2 a2 = *(uint2*)&Ts[s][cc + 8];
    uint2 a3 = *(uint2*)&Ts[s][cc + 12];
    h16* dst = xT + ((size_t)b * S_LEN + s0 + s) * CDIM + c0 + cc;
    uint4 w0 = make_uint4(a0.x, a0.y, a1.x, a1.y);
    uint4 w1 = make_uint4(a2.x, a2.y, a3.x, a3.y);
    *(uint4*)dst       = w0;
    *(uint4*)(dst + 8) = w1;
}

// ---------------------------------------------------------------------------
// Kernel 0b: convert Wqkv (1536x512) and Wout (512x512) fp32 -> fp16
// ---------------------------------------------------------------------------
__global__ __launch_bounds__(256) void wconv(
    const float* __restrict__ Wq, const float* __restrict__ Wo,
    h16* __restrict__ Wq_h, h16* __restrict__ Wo_h)
{
    const int NQ = 1536 * 512;
    const int NO = 512 * 512;
    int i = (blockIdx.x * 256 + threadIdx.x) * 4;
    if (i >= NQ + NO) return;
    float4 v;
    h16* dst;
    if (i < NQ) { v = *(const float4*)(Wq + i);        dst = Wq_h + i; }
    else        { v = *(const float4*)(Wo + (i - NQ)); dst = Wo_h + (i - NQ); }
    union { h16 h[4]; uint2 u; } pk;
    pk.h[0]=(h16)v.x; pk.h[1]=(h16)v.y; pk.h[2]=(h16)v.z; pk.h[3]=(h16)v.w;
    *(uint2*)dst = pk.u;
}

// ---------------------------------------------------------------------------
// Kernel 1: QKV projection, fp16 MFMA. q rows get *QSCALE (softmax exp2 domain).
// ---------------------------------------------------------------------------
__global__ __launch_bounds__(256) void gemm_qkv(
    const h16* __restrict__ Wh, const float* __restrict__ bqkv,
    const h16* __restrict__ xT, h16* __restrict__ qT, h16* __restrict__ kT,
    h16* __restrict__ vN)
{
    const int n0 = blockIdx.x * 128;
    const int m0 = blockIdx.y * 128;
    const int b  = blockIdx.z;
    __shared__ h16 Ws[128 * 64];
    __shared__ h16 Xs[128 * 64];

    const int tid = threadIdx.x;
    const int lid = tid & 63, w = tid >> 6;
    const int g = lid >> 4, ln = lid & 15;
    const int wm = w & 1, wn = w >> 1;
    const int srow = lid >> 3;
    const int sblk = (lid & 7) ^ (srow & 7);

    f32x4 acc[4][4];
#pragma unroll
    for (int i = 0; i < 4; i++)
#pragma unroll
        for (int j = 0; j < 4; j++) acc[i][j] = (f32x4)0.f;

    const h16* Wbase = Wh + (size_t)m0 * CDIM;
    const h16* Xbase = xT + ((size_t)b * S_LEN + n0) * CDIM;
    const bool vblk = (m0 >= 1024);

    for (int kt = 0; kt < CDIM; kt += 64) {
        __syncthreads();
#pragma unroll
        for (int i = 0; i < 4; i++) {
            const int row0 = w * 32 + i * 8;
            gll16(Wbase + (size_t)(row0 + srow) * CDIM + kt + sblk * 8, &Ws[row0 * 64]);
            gll16(Xbase + (size_t)(row0 + srow) * CDIM + kt + sblk * 8, &Xs[row0 * 64]);
        }
        __syncthreads();

#pragma unroll
        for (int kc = 0; kc < 2; kc++) {
            f16x8 af[4], bf[4];
#pragma unroll
            for (int i = 0; i < 4; i++) {
                const int ra = wm * 64 + i * 16 + ln;
                const int ca = (kc * 64 + g * 16) ^ ((ra & 7) << 4);
                af[i] = *(const f16x8*)&Ws[ra * 64 + ca / 2];
                const int rb = wn * 64 + i * 16 + ln;
                const int cb = (kc * 64 + g * 16) ^ ((rb & 7) << 4);
                bf[i] = *(const f16x8*)&Xs[rb * 64 + cb / 2];
            }
            if (!vblk) {
#pragma unroll
                for (int i = 0; i < 4; i++)
#pragma unroll
                    for (int j = 0; j < 4; j++)
                        acc[i][j] = __builtin_amdgcn_mfma_f32_16x16x32_f16(
                            af[i], bf[j], acc[i][j], 0, 0, 0);
            } else {
#pragma unroll
                for (int i = 0; i < 4; i++)
#pragma unroll
                    for (int j = 0; j < 4; j++)
                        acc[i][j] = __builtin_amdgcn_mfma_f32_16x16x32_f16(
                            bf[i], af[j], acc[i][j], 0, 0, 0);
            }
        }
    }

    if (!vblk) {
#pragma unroll
        for (int i = 0; i < 4; i++) {
            const int mb = m0 + wm * 64 + i * 16 + 4 * g;
            const float4 bv = *(const float4*)&bqkv[mb];
            const int mloc = mb & 511;
            const int hh = mloc >> 6, d0 = mloc & 63;
            const bool isq = (mb < 512);
            const float scl = isq ? QSCALE : 1.0f;
            h16* base = (isq ? qT : kT);
#pragma unroll
            for (int j = 0; j < 4; j++) {
                const int n = n0 + wn * 64 + j * 16 + ln;
                union { h16 h[4]; uint2 u; } pk;
                pk.h[0] = (h16)((acc[i][j][0] + bv.x) * scl);
                pk.h[1] = (h16)((acc[i][j][1] + bv.y) * scl);
                pk.h[2] = (h16)((acc[i][j][2] + bv.z) * scl);
                pk.h[3] = (h16)((acc[i][j][3] + bv.w) * scl);
                *(uint2*)(base + (((size_t)b * 8 + hh) * S_LEN + n) * 64 + d0) = pk.u;
            }
        }
    } else {
#pragma unroll
        for (int j = 0; j < 4; j++) {
            const int m = m0 + wm * 64 + j * 16 + ln;
            const float bias = bqkv[m];
            const int mloc = m - 1024;
            const int hh = mloc >> 6, d = mloc & 63;
            h16* base = vN + (((size_t)b * 8 + hh) * 64 + d) * S_LEN;
#pragma unroll
            for (int i = 0; i < 4; i++) {
                const int nb = n0 + wn * 64 + i * 16 + 4 * g;
                union { h16 h[4]; uint2 u; } pk;
                pk.h[0] = (h16)(acc[i][j][0] + bias);
                pk.h[1] = (h16)(acc[i][j][1] + bias);
                pk.h[2] = (h16)(acc[i][j][2] + bias);
                pk.h[3] = (h16)(acc[i][j][3] + bias);
                *(uint2*)(base + nb) = pk.u;
            }
        }
    }
}

// ---------------------------------------------------------------------------
// Kernel 2: flash attention fp16, 32x32 swapped-QK, IN-REGISTER softmax (T12).
//  - wave owns 32 queries (lane&31 = query col); P never touches LDS.
//  - S^T = mfma32x32(Kfrag, Qfrag): lane holds 32 P-values (t split w/ lane^32).
//  - P->fp16 B-frags via cvt_pkrtz + v_permlane32_swap_b32 word exchange.
//  - LDS = K/V dbuf only (32KB) -> 4 blocks/CU; 4 waves x 32q = 128q/block.
//  - defer-max; exp2 domain; K/V double-buffered via global_load_lds.
// ---------------------------------------------------------------------------
__global__ __launch_bounds__(256, 4) void attn_f16(
    const h16* __restrict__ qT, const h16* __restrict__ kT,
    const h16* __restrict__ vN, h16* __restrict__ attT)
{
    const int s0 = blockIdx.x * 128;
    const int h  = blockIdx.y;
    const int b  = blockIdx.z;
    __shared__ h16 Ks[2][64 * 64];
    __shared__ h16 Vs[2][64 * 64];

    const int tid = threadIdx.x;
    const int lid = tid & 63, w = tid >> 6;
    const int l31 = lid & 31, hi = lid >> 5;
    const int srow = lid >> 3;
    const int sblk = (lid & 7) ^ (srow & 7);

    const h16* qb = qT + ((size_t)b * 8 + h) * S_LEN * 64;
    const h16* kb = kT + ((size_t)b * 8 + h) * S_LEN * 64;
    const h16* vb = vN + ((size_t)b * 8 + h) * 64 * S_LEN;

    const int sq = s0 + w * 32 + l31;   // this lane's query row

    // Q B-frags: lane holds Q[sq][d], d = ds*16 + hi*8 + (0..7)
    f16x8 qf[4];
    {
        const h16* qrow = qb + (size_t)sq * 64;
#pragma unroll
        for (int ds = 0; ds < 4; ds++)
            qf[ds] = *(const f16x8*)(qrow + ds * 16 + hi * 8);
    }

    // prologue: stage tile 0 of K/V (16 x 8-row chunks over 4 waves)
    for (int c = w; c < 16; c += 4) {
        if (c < 8)
            gll16(kb + (size_t)(c * 8 + srow) * 64 + sblk * 8, &Ks[0][c * 8 * 64]);
        else
            gll16(vb + (size_t)((c - 8) * 8 + srow) * S_LEN + sblk * 8,
                  &Vs[0][(c - 8) * 8 * 64]);
    }
    __syncthreads();

    float m_run = -1e30f, l_run = 0.f;
    f32x16 oacc0 = (f32x16)0.f, oacc1 = (f32x16)0.f;

    int cur = 0;
    for (int kt = 0; kt < S_LEN; kt += 64, cur ^= 1) {
        // prefetch next K/V tile (drained by end-of-tile barrier)
        if (kt + 64 < S_LEN) {
            for (int c = w; c < 16; c += 4) {
                if (c < 8)
                    gll16(kb + (size_t)(kt + 64 + c * 8 + srow) * 64 + sblk * 8,
                          &Ks[cur ^ 1][c * 8 * 64]);
                else
                    gll16(vb + (size_t)((c - 8) * 8 + srow) * S_LEN + kt + 64 + sblk * 8,
                          &Vs[cur ^ 1][(c - 8) * 8 * 64]);
            }
        }
        const h16* Kc = Ks[cur];
        const h16* Vc = Vs[cur];

        // S^T[t][s]: sacc0 t=0..31, sacc1 t=32..63; lane t-rows (r&3)+8(r>>2)+4hi
        f32x16 sacc0 = (f32x16)0.f, sacc1 = (f32x16)0.f;
#pragma unroll
        for (int ds = 0; ds < 4; ds++) {
            const int bc = 2 * ds + hi;
            {
                const int row = l31;
                f16x8 kf = *(const f16x8*)&Kc[row * 64 + ((bc ^ (row & 7)) * 8)];
                sacc0 = __builtin_amdgcn_mfma_f32_32x32x16_f16(kf, qf[ds], sacc0, 0, 0, 0);
            }
            {
                const int row = 32 + l31;
                f16x8 kf = *(const f16x8*)&Kc[row * 64 + ((bc ^ (row & 7)) * 8)];
                sacc1 = __builtin_amdgcn_mfma_f32_32x32x16_f16(kf, qf[ds], sacc1, 0, 0, 0);
            }
        }

        // column max over lane's 32 values + cross-half exchange
        float mloc = -1e30f;
#pragma unroll
        for (int r = 0; r < 16; r++) {
            mloc = fmaxf(mloc, sacc0[r]);
            mloc = fmaxf(mloc, sacc1[r]);
        }
        mloc = fmaxf(mloc, __shfl_xor(mloc, 32));

        // defer-max: rescale only when tile max grew past threshold (exp2 dom)
        if (!__all(mloc <= m_run + 8.0f)) {
            const float mnew = fmaxf(m_run, mloc);
            const float resc = fexp2(m_run - mnew);
#pragma unroll
            for (int r = 0; r < 16; r++) { oacc0[r] *= resc; oacc1[r] *= resc; }
            l_run *= resc;
            m_run = mnew;
        }

        // P = exp2(S - m_run) in place; accumulate l
        float lsum = 0.f;
#pragma unroll
        for (int r = 0; r < 16; r++) {
            sacc0[r] = fexp2(sacc0[r] - m_run); lsum += sacc0[r];
        }
#pragma unroll
        for (int r = 0; r < 16; r++) {
            sacc1[r] = fexp2(sacc1[r] - m_run); lsum += sacc1[r];
        }
        l_run += lsum + __shfl_xor(lsum, 32);

        // pack P into 4 B-frags (t-slices of 16) via cvt_pk + permlane32_swap:
        // swap(pk(p[b0],p[b0+1]), pk(p[b0+4],p[b0+5])) -> frag words q0,q2
        f16x8 pf[4];
#pragma unroll
        for (int i = 0; i < 4; i++) {
            const int bse = (i & 1) * 8;
            float pv[8];
#pragma unroll
            for (int r = 0; r < 8; r++)
                pv[r] = (i < 2) ? sacc0[bse + r] : sacc1[bse + r];
            unsigned X0 = cvtpk(pv[0], pv[1]);
            unsigned X1 = cvtpk(pv[2], pv[3]);
            unsigned Y0 = cvtpk(pv[4], pv[5]);
            unsigned Y1 = cvtpk(pv[6], pv[7]);
            asm("v_permlane32_swap_b32 %0, %1" : "+v"(X0), "+v"(Y0));
            asm("v_permlane32_swap_b32 %0, %1" : "+v"(X1), "+v"(Y1));
            union { unsigned u[4]; f16x8 v; } pkk;
            pkk.u[0] = X0; pkk.u[1] = X1; pkk.u[2] = Y0; pkk.u[3] = Y1;
            pf[i] = pkk.v;
        }

        // O += mfma(Vfrag, Pfrag): out[d][s], d-tiles 0/1
#pragma unroll
        for (int i = 0; i < 4; i++) {
            const int bc = 2 * i + hi;
            {
                const int row = l31;
                f16x8 vf = *(const f16x8*)&Vc[row * 64 + ((bc ^ (row & 7)) * 8)];
                oacc0 = __builtin_amdgcn_mfma_f32_32x32x16_f16(vf, pf[i], oacc0, 0, 0, 0);
            }
            {
                const int row = 32 + l31;
                f16x8 vf = *(const f16x8*)&Vc[row * 64 + ((bc ^ (row & 7)) * 8)];
                oacc1 = __builtin_amdgcn_mfma_f32_32x32x16_f16(vf, pf[i], oacc1, 0, 0, 0);
            }
        }
        __syncthreads();   // next tile staged (vmcnt drain) + Ks/Vs reads done
    }

    // epilogue: attT[b][sq][h*64 + d]; oaccX reg 4g+r -> d = Xd*32 + 8g + 4hi + r
    const float inv = 1.0f / l_run;
    h16* ob = attT + ((size_t)b * S_LEN + sq) * CDIM + h * 64;
#pragma unroll
    for (int gi = 0; gi < 4; gi++) {
        union { h16 hh[4]; uint2 u; } p0, p1;
#pragma unroll
        for (int r = 0; r < 4; r++) {
            p0.hh[r] = (h16)(oacc0[gi * 4 + r] * inv);
            p1.hh[r] = (h16)(oacc1[gi * 4 + r] * inv);
        }
        *(uint2*)(ob + 8 * gi + 4 * hi)      = p0.u;
        *(uint2*)(ob + 32 + 8 * gi + 4 * hi) = p1.u;
    }
}

// ---------------------------------------------------------------------------
// Kernel 3: output projection. A=attT[b][n][k], B=Wout_h[m][k].
// ---------------------------------------------------------------------------
__global__ __launch_bounds__(256) void gemm_out(
    const h16* __restrict__ attT, const h16* __restrict__ Wh,
    const float* __restrict__ bout, float* __restrict__ out)
{
    const int n0 = blockIdx.x * 128;
    const int m0 = blockIdx.y * 128;
    const int b  = blockIdx.z;
    __shared__ h16 Ws[128 * 64];
    __shared__ h16 Xs[128 * 64];

    const int tid = threadIdx.x;
    const int lid = tid & 63, w = tid >> 6;
    const int g = lid >> 4, ln = lid & 15;
    const int wm = w & 1, wn = w >> 1;
    const int srow = lid >> 3;
    const int sblk = (lid & 7) ^ (srow & 7);

    f32x4 acc[4][4];
#pragma unroll
    for (int i = 0; i < 4; i++)
#pragma unroll
        for (int j = 0; j < 4; j++) acc[i][j] = (f32x4)0.f;

    const h16* Wbase = Wh + (size_t)m0 * CDIM;
    const h16* Xbase = attT + ((size_t)b * S_LEN + n0) * CDIM;

    for (int kt = 0; kt < CDIM; kt += 64) {
        __syncthreads();
#pragma unroll
        for (int i = 0; i < 4; i++) {
            const int row0 = w * 32 + i * 8;
            gll16(Wbase + (size_t)(row0 + srow) * CDIM + kt + sblk * 8, &Ws[row0 * 64]);
            gll16(Xbase + (size_t)(row0 + srow) * CDIM + kt + sblk * 8, &Xs[row0 * 64]);
        }
        __syncthreads();

#pragma unroll
        for (int kc = 0; kc < 2; kc++) {
            f16x8 af[4], bf[4];
#pragma unroll
            for (int i = 0; i < 4; i++) {
                const int ra = wm * 64 + i * 16 + ln;
                const int ca = (kc * 64 + g * 16) ^ ((ra & 7) << 4);
                af[i] = *(const f16x8*)&Ws[ra * 64 + ca / 2];
                const int rb = wn * 64 + i * 16 + ln;
                const int cb = (kc * 64 + g * 16) ^ ((rb & 7) << 4);
                bf[i] = *(const f16x8*)&Xs[rb * 64 + cb / 2];
            }
#pragma unroll
            for (int i = 0; i < 4; i++)
#pragma unroll
                for (int j = 0; j < 4; j++)
                    acc[i][j] = __builtin_amdgcn_mfma_f32_16x16x32_f16(
                        bf[i], af[j], acc[i][j], 0, 0, 0);
        }
    }

#pragma unroll
    for (int j = 0; j < 4; j++) {
        const int m = m0 + wm * 64 + j * 16 + ln;
        const float bias = bout[m];
        float* base = out + ((size_t)b * CDIM + m) * S_LEN;
#pragma unroll
        for (int i = 0; i < 4; i++) {
            const int nb = n0 + wn * 64 + i * 16 + 4 * g;
            float4 o;
            o.x = acc[i][j][0] + bias;
            o.y = acc[i][j][1] + bias;
            o.z = acc[i][j][2] + bias;
            o.w = acc[i][j][3] + bias;
            *(float4*)(base + nb) = o;
        }
    }
}

// ---------------------------------------------------------------------------
extern "C" void kernel_launch(void* const* d_in, const int* in_sizes, int n_in,
                              void* d_out, int out_size, void* d_ws, size_t ws_size,
                              hipStream_t stream)
{
    const float* x    = (const float*)d_in[0];
    const float* Wqkv = (const float*)d_in[1];
    const float* bqkv = (const float*)d_in[2];
    const float* Wout = (const float*)d_in[3];
    const float* bout = (const float*)d_in[4];
    float* out = (float*)d_out;

    h16* xT   = (h16*)d_ws;                          // [4][2304][512]
    h16* Wq_h = xT   + (size_t)4 * S_LEN * CDIM;     // [1536][512]
    h16* Wo_h = Wq_h + (size_t)1536 * 512;           // [512][512]
    h16* qT   = Wo_h + (size_t)512 * 512;            // [4][8][2304][64]
    h16* kT   = qT   + (size_t)4 * 8 * S_LEN * 64;
    h16* vN   = kT   + (size_t)4 * 8 * S_LEN * 64;   // [4][8][64][2304]
    h16* attT = vN   + (size_t)4 * 8 * S_LEN * 64;   // [4][2304][512]

    xpose_x <<<dim3(36, 8, 4),  256, 0, stream>>>(x, xT);
    wconv   <<<1024,            256, 0, stream>>>(Wqkv, Wout, Wq_h, Wo_h);
    gemm_qkv<<<dim3(18, 12, 4), 256, 0, stream>>>(Wq_h, bqkv, xT, qT, kT, vN);
    attn_f16<<<dim3(18, 8, 4),  256, 0, stream>>>(qT, kT, vN, attT);
    gemm_out<<<dim3(18, 4, 4),  256, 0, stream>>>(attT, Wo_h, bout, out);
}